// Round 2
// baseline (166.734 us; speedup 1.0000x reference)
//
#include <hip/hip_runtime.h>

// AdderNet conv: out[n,co,i,j] = -sum_{ci,kh,kw} |x[n,ci,i+kh,j+kw] - W[co,ci,kh,kw]|
// x: (16,5,512,512) fp32, W: (5,5,3,3) fp32, out: (16,5,510,510) fp32
//
// R2 structure: ci loop rolled with an 18-float live window; taps x rows x co
// fully unrolled against 20 persistent accumulators. x loaded once per thread.

#define KK 3
#define NB 16
#define CI 5
#define CO 5
#define H 512
#define WD 512
#define HO 510
#define WO 510
#define TW 64   // tile width  (columns, = lanes)
#define TH 16   // tile height (4 ty groups x 4 rows/thread)

__global__ __launch_bounds__(256)
void adder2d_kernel(const float* __restrict__ x,
                    const float* __restrict__ Wg,
                    float* __restrict__ out) {
    const int tx = threadIdx.x & 63;     // column within tile
    const int ty = threadIdx.x >> 6;     // 0..3 row group
    const int j0 = blockIdx.x * TW;
    const int i0 = blockIdx.y * TH;
    const int n  = blockIdx.z;

    const int j     = j0 + tx;           // output column
    const int ibase = i0 + ty * 4;       // first of this thread's 4 output rows

    // Clamped load coordinates. jc: lanes with j>=WO are invalid anyway, clamp
    // so jc..jc+2 <= 511. Per-row clamp keeps valid rows exactly aligned.
    const int jc = j < WO ? j : (WO - 1);
    int rowoff[6];
    #pragma unroll
    for (int r = 0; r < 6; ++r) {
        int gi = ibase + r;
        gi = gi < H ? gi : (H - 1);
        rowoff[r] = gi * WD;
    }

    const float* xn = x + (size_t)n * CI * H * WD + jc;

    float acc[CO][4];
    #pragma unroll
    for (int co = 0; co < CO; ++co)
        #pragma unroll
        for (int r = 0; r < 4; ++r) acc[co][r] = 0.f;

    // ci rolled: live set per iteration = 18-float window + 20 acc.
    #pragma unroll 1
    for (int ci = 0; ci < CI; ++ci) {
        const float* p = xn + (size_t)ci * H * WD;
        float xw[6][KK];
        #pragma unroll
        for (int r = 0; r < 6; ++r) {
            const float* rp = p + rowoff[r];
            xw[r][0] = rp[0];
            xw[r][1] = rp[1];
            xw[r][2] = rp[2];
        }
        const float* wp = Wg + ci * (KK * KK);   // W[co][ci][kh][kw], co stride 45
        #pragma unroll
        for (int kh = 0; kh < KK; ++kh) {
            #pragma unroll
            for (int kw = 0; kw < KK; ++kw) {
                const int widx = kh * KK + kw;
                float w0 = wp[0 * 45 + widx];
                float w1 = wp[1 * 45 + widx];
                float w2 = wp[2 * 45 + widx];
                float w3 = wp[3 * 45 + widx];
                float w4 = wp[4 * 45 + widx];
                #pragma unroll
                for (int r = 0; r < 4; ++r) {
                    const float xv = xw[kh + r][kw];
                    acc[0][r] += fabsf(xv - w0);
                    acc[1][r] += fabsf(xv - w1);
                    acc[2][r] += fabsf(xv - w2);
                    acc[3][r] += fabsf(xv - w3);
                    acc[4][r] += fabsf(xv - w4);
                }
            }
        }
    }

    if (j < WO) {
        float* outn = out + (size_t)n * CO * HO * WO;
        #pragma unroll
        for (int co = 0; co < CO; ++co) {
            float* outc = outn + (size_t)co * HO * WO;
            #pragma unroll
            for (int r = 0; r < 4; ++r) {
                const int i = ibase + r;
                if (i < HO) outc[(size_t)i * WO + j] = -acc[co][r];
            }
        }
    }
}

extern "C" void kernel_launch(void* const* d_in, const int* in_sizes, int n_in,
                              void* d_out, int out_size, void* d_ws, size_t ws_size,
                              hipStream_t stream) {
    const float* x  = (const float*)d_in[0];
    const float* Wg = (const float*)d_in[1];
    float* out      = (float*)d_out;

    dim3 grid((WO + TW - 1) / TW,   // 8
              (HO + TH - 1) / TH,   // 32
              NB);                  // 16
    dim3 block(256);
    adder2d_kernel<<<grid, block, 0, stream>>>(x, Wg, out);
}